// Round 11
// baseline (579.431 us; speedup 1.0000x reference)
//
#include <hip/hip_runtime.h>
#include <stdint.h>

typedef short bf16x8 __attribute__((ext_vector_type(8)));
typedef float f32x4 __attribute__((ext_vector_type(4)));
typedef unsigned short u16x4 __attribute__((ext_vector_type(4)));

__device__ __forceinline__ unsigned short f2b(float f) {
  union { float f; unsigned u; } v; v.f = f;
  unsigned r = v.u + 0x7fffu + ((v.u >> 16) & 1u);
  return (unsigned short)(r >> 16);
}
__device__ __forceinline__ float fsigm(float x) { return 1.f / (1.f + __expf(-x)); }
__device__ __forceinline__ float ftanh(float x) {
  float t = __expf(-2.f * fabsf(x));
  float r = (1.f - t) / (1.f + t);
  return copysignf(r, x);
}
__device__ __forceinline__ void nts4(float* p, f32x4 v) {  // 16B-aligned NT store
  __builtin_nontemporal_store(v, (f32x4*)p);
}

// ---------------- fused transpose+convert: f32[R][C] -> bf16 out[C][R], 12 matrices ----------------
struct TD { const float* in; unsigned short* out; int R, C; };
struct TDs { TD d[12]; };

__global__ __launch_bounds__(256) void tconv_all(TDs ds) {
  TD t = ds.d[blockIdx.z];
  int c0 = blockIdx.x * 32, r0 = blockIdx.y * 32;
  if (c0 >= t.C || r0 >= t.R) return;
  __shared__ float tl[32][33];
  int tx = threadIdx.x & 31, ty = threadIdx.x >> 5;
  #pragma unroll
  for (int i = 0; i < 32; i += 8) {
    int r = r0 + ty + i, c = c0 + tx;
    tl[ty + i][tx] = (r < t.R && c < t.C) ? t.in[(size_t)r * t.C + c] : 0.f;
  }
  __syncthreads();
  #pragma unroll
  for (int i = 0; i < 32; i += 8) {
    int c = c0 + ty + i, r = r0 + tx;
    if (c < t.C && r < t.R) t.out[(size_t)c * t.R + r] = f2b(tl[tx][ty + i]);
  }
}

// ================= megakernel: 32 rows end-to-end per block (1024 thr, 16 waves) =================
// Swapped-operand MFMA everywhere: D lane&15 = batchrow, (lane>>4)*4+reg = out-col.
__global__ __launch_bounds__(1024, 4) void mega_k(
    const float* __restrict__ obs,                                    // [8192][1024] f32
    const unsigned short* __restrict__ W1T, const float* __restrict__ bb1,   // [512][1024]
    const unsigned short* __restrict__ W2T, const float* __restrict__ bb2,   // [512][512]
    const unsigned short* __restrict__ polT, const float* __restrict__ pol_b,// [16][512]
    const unsigned short* __restrict__ yT,  const float* __restrict__ y_b,   // [600][512]
    const unsigned short* __restrict__ ciT, const float* __restrict__ ci_b,  // [128][512]
    const unsigned short* __restrict__ whhT,                                 // [512][128]
    const float* __restrict__ w_ih, const float* __restrict__ b_ih, const float* __restrict__ b_hh,
    const unsigned short* __restrict__ w1cat,                                // [384][128]
    const float* __restrict__ zb1, const float* __restrict__ qb1, const float* __restrict__ ab1,
    const unsigned short* __restrict__ w2cat,                                // [1217][128]
    const float* __restrict__ zb2, const float* __restrict__ qb2, const float* __restrict__ ab2,
    float* __restrict__ oL, float* __restrict__ oY,
    float* __restrict__ oz, float* __restrict__ oq, float* __restrict__ oa) {
  __shared__ __align__(16) uint8_t smem[125440];
  unsigned short (*obsS)[520] = (unsigned short(*)[520])(smem);            // P1
  unsigned short (*h1S)[520]  = (unsigned short(*)[520])(smem + 33280);    // P1->P2
  unsigned short (*embS)[520] = (unsigned short(*)[520])(smem + 66560);    // P2->P3
  unsigned short (*hstS)[136] = (unsigned short(*)[136])(smem + 99840);    // P3->P4
  float          (*cstS)[132] = (float(*)[132])(smem + 108544);            // P3->P4
  float          (*GS)[516]   = (float(*)[516])(smem);                     // P4 (over obsS/h1S)
  unsigned short (*hdS)[392]  = (unsigned short(*)[392])(smem + 66560);    // P4 (over embS)

  const int tid = threadIdx.x;
  const int w = tid >> 6, lane = tid & 63;
  const int lr = lane & 15, lk = lane >> 4;
  const int r0 = blockIdx.x * 32;

  // ---------- P1: backbone gemm1 (K=1024, two 512-wide k-passes with obs staging) ----------
  {
    f32x4 acc[2][2] = {};  // [rf][cf], wave cols 32w+16cf
    #pragma unroll
    for (int p = 0; p < 2; p++) {
      // stage obs half: rows 32, cols p*512..+511, f32 -> bf16
      {
        int row = tid >> 5, cbase = (tid & 31) * 4;
        const float* src = obs + (size_t)(r0 + row) * 1024 + p * 512;
        #pragma unroll
        for (int i = 0; i < 4; i++) {
          int c = cbase + i * 128;
          float4 f = *(const float4*)(src + c);
          u16x4 v; v[0] = f2b(f.x); v[1] = f2b(f.y); v[2] = f2b(f.z); v[3] = f2b(f.w);
          *(u16x4*)&obsS[row][c] = v;
        }
      }
      __syncthreads();
      for (int ks = 0; ks < 16; ks++) {
        bf16x8 av[2], bv[2];
        #pragma unroll
        for (int cf = 0; cf < 2; cf++)
          av[cf] = *(const bf16x8*)(W1T + (size_t)(32 * w + 16 * cf + lr) * 1024 + p * 512 + ks * 32 + lk * 8);
        #pragma unroll
        for (int rf = 0; rf < 2; rf++)
          bv[rf] = *(const bf16x8*)&obsS[16 * rf + lr][ks * 32 + lk * 8];
        #pragma unroll
        for (int cf = 0; cf < 2; cf++)
          #pragma unroll
          for (int rf = 0; rf < 2; rf++)
            acc[rf][cf] = __builtin_amdgcn_mfma_f32_16x16x32_bf16(av[cf], bv[rf], acc[rf][cf], 0, 0, 0);
      }
      __syncthreads();
    }
    #pragma unroll
    for (int rf = 0; rf < 2; rf++)
      #pragma unroll
      for (int cf = 0; cf < 2; cf++) {
        int col = 32 * w + 16 * cf + lk * 4;
        f32x4 bb = *(const f32x4*)(bb1 + col);
        u16x4 v;
        #pragma unroll
        for (int rr = 0; rr < 4; rr++) v[rr] = f2b(fmaxf(acc[rf][cf][rr] + bb[rr], 0.f));
        *(u16x4*)&h1S[16 * rf + lr][col] = v;
      }
  }
  __syncthreads();

  // ---------- P2: gemm2 (K=512) h1S -> embS ----------
  {
    f32x4 acc[2][2] = {};
    for (int ks = 0; ks < 16; ks++) {
      bf16x8 av[2], bv[2];
      #pragma unroll
      for (int cf = 0; cf < 2; cf++)
        av[cf] = *(const bf16x8*)(W2T + (size_t)(32 * w + 16 * cf + lr) * 512 + ks * 32 + lk * 8);
      #pragma unroll
      for (int rf = 0; rf < 2; rf++)
        bv[rf] = *(const bf16x8*)&h1S[16 * rf + lr][ks * 32 + lk * 8];
      #pragma unroll
      for (int cf = 0; cf < 2; cf++)
        #pragma unroll
        for (int rf = 0; rf < 2; rf++)
          acc[rf][cf] = __builtin_amdgcn_mfma_f32_16x16x32_bf16(av[cf], bv[rf], acc[rf][cf], 0, 0, 0);
    }
    #pragma unroll
    for (int rf = 0; rf < 2; rf++)
      #pragma unroll
      for (int cf = 0; cf < 2; cf++) {
        int col = 32 * w + 16 * cf + lk * 4;
        f32x4 bb = *(const f32x4*)(bb2 + col);
        u16x4 v;
        #pragma unroll
        for (int rr = 0; rr < 4; rr++) v[rr] = f2b(fmaxf(acc[rf][cf][rr] + bb[rr], 0.f));
        *(u16x4*)&embS[16 * rf + lr][col] = v;
      }
  }
  __syncthreads();

  // ---------- P3: ci (waves 0-7), pol (wave 8), y (all waves) ----------
  if (w < 8) {  // ci frag w: cols 16w..+15 -> cstS, hstS
    f32x4 acc[2] = {};
    for (int ks = 0; ks < 16; ks++) {
      bf16x8 av = *(const bf16x8*)(ciT + (size_t)(16 * w + lr) * 512 + ks * 32 + lk * 8);
      #pragma unroll
      for (int rf = 0; rf < 2; rf++) {
        bf16x8 bv = *(const bf16x8*)&embS[16 * rf + lr][ks * 32 + lk * 8];
        acc[rf] = __builtin_amdgcn_mfma_f32_16x16x32_bf16(av, bv, acc[rf], 0, 0, 0);
      }
    }
    int col = 16 * w + lk * 4;
    f32x4 bb = *(const f32x4*)(ci_b + col);
    #pragma unroll
    for (int rf = 0; rf < 2; rf++) {
      f32x4 c = acc[rf] + bb;
      *(f32x4*)&cstS[16 * rf + lr][col] = c;
      u16x4 h; 
      #pragma unroll
      for (int rr = 0; rr < 4; rr++) h[rr] = f2b(ftanh(c[rr]));
      *(u16x4*)&hstS[16 * rf + lr][col] = h;
    }
  } else if (w == 8) {  // pol: 16 cols
    f32x4 acc[2] = {};
    for (int ks = 0; ks < 16; ks++) {
      bf16x8 av = *(const bf16x8*)(polT + (size_t)lr * 512 + ks * 32 + lk * 8);
      #pragma unroll
      for (int rf = 0; rf < 2; rf++) {
        bf16x8 bv = *(const bf16x8*)&embS[16 * rf + lr][ks * 32 + lk * 8];
        acc[rf] = __builtin_amdgcn_mfma_f32_16x16x32_bf16(av, bv, acc[rf], 0, 0, 0);
      }
    }
    f32x4 bb = *(const f32x4*)(pol_b + lk * 4);
    #pragma unroll
    for (int rf = 0; rf < 2; rf++)
      *(f32x4*)(oL + (size_t)(r0 + 16 * rf + lr) * 16 + lk * 4) = acc[rf] + bb;
  }
  // y head: frags w, w+16, w+32 (<38)
  #pragma unroll
  for (int ii = 0; ii < 3; ii++) {
    int f = w + ii * 16;
    if (f >= 38) break;
    int yrow = min(f * 16 + lr, 599);
    f32x4 acc[2] = {};
    for (int ks = 0; ks < 16; ks++) {
      bf16x8 av = *(const bf16x8*)(yT + (size_t)yrow * 512 + ks * 32 + lk * 8);
      #pragma unroll
      for (int rf = 0; rf < 2; rf++) {
        bf16x8 bv = *(const bf16x8*)&embS[16 * rf + lr][ks * 32 + lk * 8];
        acc[rf] = __builtin_amdgcn_mfma_f32_16x16x32_bf16(av, bv, acc[rf], 0, 0, 0);
      }
    }
    int col = f * 16 + lk * 4;
    if (col + 3 < 600) {
      f32x4 bb = *(const f32x4*)(y_b + col);
      #pragma unroll
      for (int rf = 0; rf < 2; rf++)
        nts4(oY + (size_t)(r0 + 16 * rf + lr) * 600 + col, acc[rf] + bb);
    }
  }
  __syncthreads();

  // ---------- P4: LSTM 16 steps with fused heads ----------
  const int j = tid & 127;
  const int rb = tid >> 7;  // 0..7
  const float bs0 = b_ih[j]       + b_hh[j];
  const float bs1 = b_ih[j + 128] + b_hh[j + 128];
  const float bs2 = b_ih[j + 256] + b_hh[j + 256];
  const float bs3 = b_ih[j + 384] + b_hh[j + 384];

  for (int a = 0; a < 16; a++) {
    // (a) gate gemm: G[row][gatecol], wave w owns gate cols 32w..+31 (normal orientation)
    {
      f32x4 acc[2][2] = {};
      #pragma unroll
      for (int ks = 0; ks < 4; ks++) {
        bf16x8 af0 = *(const bf16x8*)&hstS[lr][ks * 32 + lk * 8];
        bf16x8 af1 = *(const bf16x8*)&hstS[16 + lr][ks * 32 + lk * 8];
        #pragma unroll
        for (int nj = 0; nj < 2; nj++) {
          bf16x8 wv = *(const bf16x8*)(whhT + (size_t)(32 * w + 16 * nj + lr) * 128 + ks * 32 + lk * 8);
          acc[0][nj] = __builtin_amdgcn_mfma_f32_16x16x32_bf16(af0, wv, acc[0][nj], 0, 0, 0);
          acc[1][nj] = __builtin_amdgcn_mfma_f32_16x16x32_bf16(af1, wv, acc[1][nj], 0, 0, 0);
        }
      }
      #pragma unroll
      for (int rf = 0; rf < 2; rf++)
        #pragma unroll
        for (int nj = 0; nj < 2; nj++)
          #pragma unroll
          for (int rr = 0; rr < 4; rr++)
            GS[rf * 16 + lk * 4 + rr][32 * w + 16 * nj + lr] = acc[rf][nj][rr];
    }
    __syncthreads();

    // (b) gate update -> cstS, hstS
    {
      const float* ig = w_ih + a * 512;
      const float ig0 = ig[j], ig1 = ig[j + 128], ig2 = ig[j + 256], ig3 = ig[j + 384];
      #pragma unroll
      for (int it = 0; it < 4; it++) {
        int r = rb + it * 8;
        float gi = GS[r][j]       + ig0 + bs0;
        float gf = GS[r][j + 128] + ig1 + bs1;
        float gg = GS[r][j + 256] + ig2 + bs2;
        float go = GS[r][j + 384] + ig3 + bs3;
        float c = cstS[r][j];
        float cn = fsigm(gf) * c + fsigm(gi) * ftanh(gg);
        float h = fsigm(go) * ftanh(cn);
        cstS[r][j] = cn;
        hstS[r][j] = f2b(h);
      }
    }
    __syncthreads();

    // (c) heads hidden: 24 frags over waves (f = w, w+16), swapped orientation -> hdS
    {
      bf16x8 hb[2][4];
      #pragma unroll
      for (int rf = 0; rf < 2; rf++)
        #pragma unroll
        for (int ks = 0; ks < 4; ks++)
          hb[rf][ks] = *(const bf16x8*)&hstS[16 * rf + lr][ks * 32 + lk * 8];
      #pragma unroll
      for (int ii = 0; ii < 2; ii++) {
        int f = w + ii * 16;
        if (f >= 24) break;
        int head = f >> 3;
        const float* b1 = (head == 0) ? zb1 : (head == 1) ? qb1 : ab1;
        bf16x8 w1v[4];
        #pragma unroll
        for (int ks = 0; ks < 4; ks++)
          w1v[ks] = *(const bf16x8*)(w1cat + (size_t)(f * 16 + lr) * 128 + ks * 32 + lk * 8);
        f32x4 acc[2] = {};
        #pragma unroll
        for (int ks = 0; ks < 4; ks++)
          #pragma unroll
          for (int rf = 0; rf < 2; rf++)
            acc[rf] = __builtin_amdgcn_mfma_f32_16x16x32_bf16(w1v[ks], hb[rf][ks], acc[rf], 0, 0, 0);
        int col = (f & 7) * 16 + lk * 4;
        f32x4 bb = *(const f32x4*)(b1 + col);
        #pragma unroll
        for (int rf = 0; rf < 2; rf++) {
          u16x4 v;
          #pragma unroll
          for (int rr = 0; rr < 4; rr++) v[rr] = f2b(fmaxf(acc[rf][rr] + bb[rr], 0.f));
          *(u16x4*)&hdS[16 * rf + lr][f * 16 + lk * 4] = v;
        }
      }
    }
    __syncthreads();

    // (d) heads out: 77 frags (z 38 | q 38 | a 1), f = w + 16*ii; NT stores for z/a, plain for q
    #pragma unroll
    for (int ii = 0; ii < 5; ii++) {
      int f = w + ii * 16;
      if (f > 76) break;
      int head = (f < 38) ? 0 : (f < 76) ? 1 : 2;
      int fz = f - ((head == 0) ? 0 : (head == 1) ? 38 : 76);
      int Nh = (head == 0) ? 600 : (head == 1) ? 601 : 16;
      int wbase = (head == 0) ? 0 : (head == 1) ? 600 : 1201;
      const float* b2 = (head == 0) ? zb2 : (head == 1) ? qb2 : ab2;
      float* O = (head == 0) ? oz : (head == 1) ? oq : oa;

      int wrow = wbase + min(fz * 16 + lr, Nh - 1);
      f32x4 acc[2] = {};
      #pragma unroll
      for (int ks = 0; ks < 4; ks++) {
        bf16x8 w2v = *(const bf16x8*)(w2cat + (size_t)wrow * 128 + ks * 32 + lk * 8);
        #pragma unroll
        for (int rf = 0; rf < 2; rf++) {
          bf16x8 hv = *(const bf16x8*)&hdS[16 * rf + lr][head * 128 + ks * 32 + lk * 8];
          acc[rf] = __builtin_amdgcn_mfma_f32_16x16x32_bf16(w2v, hv, acc[rf], 0, 0, 0);
        }
      }
      int col = fz * 16 + lk * 4;
      if (col + 3 < Nh) {
        f32x4 bb = *(const f32x4*)(b2 + col);
        #pragma unroll
        for (int rf = 0; rf < 2; rf++) {
          size_t orow = (size_t)((r0 + 16 * rf + lr) * 16 + a);
          f32x4 v = acc[rf] + bb;
          if (head == 1) __builtin_memcpy(O + orow * Nh + col, &v, 16);  // q rows 4B-aligned
          else           nts4(O + orow * Nh + col, v);                   // z/a rows 16B-aligned
        }
      } else if (col < Nh) {
        #pragma unroll
        for (int rf = 0; rf < 2; rf++) {
          size_t orow = (size_t)((r0 + 16 * rf + lr) * 16 + a);
          #pragma unroll
          for (int rr = 0; rr < 4; rr++)
            if (col + rr < Nh) O[orow * Nh + col + rr] = acc[rf][rr] + b2[col + rr];
        }
      }
    }
    __syncthreads();
  }
}

extern "C" void kernel_launch(void* const* d_in, const int* in_sizes, int n_in,
                              void* d_out, int out_size, void* d_ws, size_t ws_size,
                              hipStream_t stream) {
  const float* obs   = (const float*)d_in[0];
  const float* bb_w1 = (const float*)d_in[1];
  const float* bb_b1 = (const float*)d_in[2];
  const float* bb_w2 = (const float*)d_in[3];
  const float* bb_b2 = (const float*)d_in[4];
  const float* pol_w = (const float*)d_in[5];
  const float* pol_b = (const float*)d_in[6];
  const float* y_w   = (const float*)d_in[7];
  const float* y_b   = (const float*)d_in[8];
  const float* ci_w  = (const float*)d_in[9];
  const float* ci_b  = (const float*)d_in[10];
  const float* w_ih  = (const float*)d_in[11];
  const float* w_hh  = (const float*)d_in[12];
  const float* b_ih  = (const float*)d_in[13];
  const float* b_hh  = (const float*)d_in[14];
  const float* z_w1  = (const float*)d_in[15];
  const float* z_b1  = (const float*)d_in[16];
  const float* z_w2  = (const float*)d_in[17];
  const float* z_b2  = (const float*)d_in[18];
  const float* q_w1  = (const float*)d_in[19];
  const float* q_b1  = (const float*)d_in[20];
  const float* q_w2  = (const float*)d_in[21];
  const float* q_b2  = (const float*)d_in[22];
  const float* a_w1  = (const float*)d_in[23];
  const float* a_b1  = (const float*)d_in[24];
  const float* a_w2  = (const float*)d_in[25];
  const float* a_b2  = (const float*)d_in[26];

  float* out = (float*)d_out;
  float* out_logits = out;                 // [8192][16]
  float* out_y      = out + 131072;        // [8192][600]
  float* out_z      = out + 5046272;       // [131072][600]
  float* out_q      = out + 83689472;      // [131072][601]
  float* out_a      = out + 162463744;     // [131072][16]

  uint8_t* ws = (uint8_t*)d_ws;
  size_t off = 0;
  auto alc = [&](size_t bytes) -> void* {
    void* p = ws + off;
    off = (off + bytes + 255) & ~(size_t)255;
    return p;
  };
  unsigned short* W1T  = (unsigned short*)alc((size_t)512 * 1024 * 2);
  unsigned short* W2T  = (unsigned short*)alc((size_t)512 * 512 * 2);
  unsigned short* polT = (unsigned short*)alc((size_t)16 * 512 * 2);
  unsigned short* yT   = (unsigned short*)alc((size_t)600 * 512 * 2);
  unsigned short* ciT  = (unsigned short*)alc((size_t)128 * 512 * 2);
  unsigned short* whhT = (unsigned short*)alc((size_t)512 * 128 * 2);
  // w1cat contiguous: z|q|a (each 32768 B, 256-aligned -> no gaps)
  unsigned short* zw1T = (unsigned short*)alc((size_t)128 * 128 * 2);
  unsigned short* qw1T = (unsigned short*)alc((size_t)128 * 128 * 2);
  unsigned short* aw1T = (unsigned short*)alc((size_t)128 * 128 * 2);
  // w2cat contiguous: z|q|a (153600/153856/4096 B, all 256-multiples)
  unsigned short* zw2T = (unsigned short*)alc((size_t)600 * 128 * 2);
  unsigned short* qw2T = (unsigned short*)alc((size_t)601 * 128 * 2);
  unsigned short* aw2T = (unsigned short*)alc((size_t)16 * 128 * 2);
  (void)ws_size; (void)in_sizes; (void)n_in; (void)out_size;
  (void)zw1T; (void)qw1T; (void)aw1T; (void)qw2T; (void)aw2T;

  dim3 B256(256);

  TDs td;
  td.d[0]  = {bb_w1, W1T, 1024, 512};
  td.d[1]  = {bb_w2, W2T, 512, 512};
  td.d[2]  = {pol_w, polT, 512, 16};
  td.d[3]  = {y_w,   yT,   512, 600};
  td.d[4]  = {ci_w,  ciT,  512, 128};
  td.d[5]  = {w_hh,  whhT, 128, 512};
  td.d[6]  = {z_w1,  zw1T, 128, 128};
  td.d[7]  = {z_w2,  zw2T, 128, 600};
  td.d[8]  = {q_w1,  qw1T, 128, 128};
  td.d[9]  = {q_w2,  qw2T, 128, 601};
  td.d[10] = {a_w1,  aw1T, 128, 128};
  td.d[11] = {a_w2,  aw2T, 128, 16};
  tconv_all<<<dim3(19, 32, 12), B256, 0, stream>>>(td);

  // end-to-end megakernel: 256 blocks x 32 rows, 1 block/CU, stores start draining immediately
  mega_k<<<dim3(256), dim3(1024), 0, stream>>>(
      obs, W1T, bb_b1, W2T, bb_b2,
      polT, pol_b, yT, y_b, ciT, ci_b,
      whhT, w_ih, b_ih, b_hh,
      zw1T, z_b1, q_b1, a_b1,
      zw2T, z_b2, q_b2, a_b2,
      out_logits, out_y, out_z, out_q, out_a);
}